// Round 2
// baseline (382.224 us; speedup 1.0000x reference)
//
#include <hip/hip_runtime.h>
#include <stdint.h>
#include <stddef.h>

// T=32768, D1=D2=512, DIN=1024, HID=768, SZ=512
// K0a: Xb(bf16)[T,1024] = concat(x1,x2)
// K0b: WlT(bf16)[768,1024], WeT(bf16)[512,768], Wf8(fp8 e4m3, x16)[512,512]=Wf^T
// K1 : H(bf16)[T,768]  = Xb @ Wl + b          (MFMA bf16, 128x128 tile, register staging)
// K2 : Z32(f32)[T,512] = sigmoid(H @ We)      (same GEMM, f32 out; overlays Xb)
// K3 : r(f32)[T]       = tanh(Z32 @ Wr)
// K4 : chunk-parallel recurrence (4096 chunks x 8 steps, 4 warmup steps;
//      contraction/step ~2.6e-3 -> truncation err ~5e-11). W_forget resident
//      in VGPRs as fp8 B-fragments; state fp32 in regs, fp8 copy in LDS for MFMA.

typedef __attribute__((ext_vector_type(8))) short bf16x8;
typedef __attribute__((ext_vector_type(4))) float f32x4;

__device__ __forceinline__ unsigned short f32_to_bf16(float f) {
  union { float f; unsigned u; } v; v.f = f;
  unsigned u = v.u;
  return (unsigned short)((u + 0x7fffu + ((u >> 16) & 1u)) >> 16);  // RNE
}
__device__ __forceinline__ float bf16_to_f32(unsigned short h) {
  union { unsigned u; float f; } v; v.u = ((unsigned)h) << 16; return v.f;
}

// OCP e4m3fn encode, RNE. |x| here is always < 32.
__device__ __forceinline__ unsigned char f32_to_e4m3(float f) {
  float a = fabsf(f);
  unsigned char s = (unsigned char)((__float_as_uint(f) >> 24) & 0x80u);
  if (a >= 448.0f) return s | 0x7Eu;
  if (a < 0.015625f) {
    unsigned m = (unsigned)rintf(a * 512.0f);
    return s | (unsigned char)m;
  }
  unsigned u = __float_as_uint(a);
  unsigned r = u + 0x7FFFFu + ((u >> 20) & 1u);
  unsigned e = (r >> 23) - 120u;
  unsigned m = (r >> 20) & 7u;
  if (e >= 16u) return s | 0x7Eu;
  return s | (unsigned char)((e << 3) | m);
}

// ---------------- K0a ----------------
__global__ void k_convert_x(const float* __restrict__ x1, const float* __restrict__ x2,
                            unsigned short* __restrict__ Xb) {
  int id = blockIdx.x * 256 + threadIdx.x;     // exactly T*1024/4
  int t  = id >> 8;
  int c4 = (id & 255) * 4;
  float4 v;
  if (c4 < 512) v = *(const float4*)(x1 + (size_t)t * 512 + c4);
  else          v = *(const float4*)(x2 + (size_t)t * 512 + (c4 - 512));
  ushort4 o;
  o.x = f32_to_bf16(v.x); o.y = f32_to_bf16(v.y);
  o.z = f32_to_bf16(v.z); o.w = f32_to_bf16(v.w);
  *(ushort4*)(Xb + (size_t)t * 1024 + c4) = o;
}

// ---------------- K0b ----------------
__global__ void k_convert_w(const float* __restrict__ Wl, const float* __restrict__ We,
                            const float* __restrict__ Wf,
                            unsigned short* __restrict__ WlT, unsigned short* __restrict__ WeT,
                            unsigned char* __restrict__ Wf8) {
  int id = blockIdx.x * 256 + threadIdx.x;     // exactly 1441792
  if (id < 786432) {                            // WlT[n][k] = Wl[k][n]
    int n = id >> 10, k = id & 1023;
    WlT[id] = f32_to_bf16(Wl[(size_t)k * 768 + n]);
  } else if (id < 1179648) {                    // WeT[n][k] = We[k][n]
    int j = id - 786432;
    int n = j / 768, k = j - n * 768;
    WeT[j] = f32_to_bf16(We[(size_t)k * 512 + n]);
  } else {                                      // Wf8[n][k] = fp8(16 * Wf[k][n])
    int j = id - 1179648;
    int n = j >> 9, k = j & 511;
    Wf8[j] = f32_to_e4m3(Wf[(size_t)k * 512 + n] * 16.0f);
  }
}

// ---------------- K1/K2: bf16 MFMA GEMM, C = A[MxK] @ B (B as B^T[NxK]) --------
// Register staging (global vec-load -> ds_write_b128). MODE 0: bf16 out, +bias.
// MODE 1: f32 out, sigmoid.
template <int MODE>
__global__ void k_gemm_bt(const unsigned short* __restrict__ A,
                          const unsigned short* __restrict__ Bt,
                          const float* __restrict__ bias,
                          unsigned short* __restrict__ Cb,
                          float* __restrict__ Cf,
                          int M, int N, int K) {
  __shared__ unsigned short As[128 * 32];
  __shared__ unsigned short Bs[128 * 32];
  const int tid = threadIdx.x;
  const int wv = tid >> 6, lane = tid & 63;
  const int nb = N >> 7;
  const int bm = blockIdx.x / nb, bn = blockIdx.x % nb;
  const int wm = wv >> 1, wn = wv & 1;          // 2x2 waves, 64x64 each
  f32x4 acc[4][4];
#pragma unroll
  for (int i = 0; i < 4; ++i)
#pragma unroll
    for (int j = 0; j < 4; ++j) acc[i][j] = f32x4{0.f, 0.f, 0.f, 0.f};

  const unsigned short* Ag = A + (size_t)(bm * 128 + (tid >> 2)) * K + (tid & 3) * 8;
  const unsigned short* Bg = Bt + (size_t)(bn * 128 + (tid >> 2)) * K + (tid & 3) * 8;
  const int sidx = (tid >> 2) * 32 + (tid & 3) * 8;   // staging elem index (row, k)
  const int lm = lane & 15;
  const int qk = (lane >> 4) * 8;

  for (int k0 = 0; k0 < K; k0 += 32) {
    bf16x8 a0 = *(const bf16x8*)(Ag + k0);
    bf16x8 a1 = *(const bf16x8*)(Ag + k0 + (size_t)64 * K);
    bf16x8 b0 = *(const bf16x8*)(Bg + k0);
    bf16x8 b1 = *(const bf16x8*)(Bg + k0 + (size_t)64 * K);
    __syncthreads();                            // previous iter's LDS reads done
    *(bf16x8*)(As + sidx)        = a0;
    *(bf16x8*)(As + sidx + 2048) = a1;
    *(bf16x8*)(Bs + sidx)        = b0;
    *(bf16x8*)(Bs + sidx + 2048) = b1;
    __syncthreads();
    bf16x8 af[4], bfr[4];
#pragma unroll
    for (int mt = 0; mt < 4; ++mt)
      af[mt] = *(const bf16x8*)(As + (wm * 64 + mt * 16 + lm) * 32 + qk);
#pragma unroll
    for (int nt = 0; nt < 4; ++nt)
      bfr[nt] = *(const bf16x8*)(Bs + (wn * 64 + nt * 16 + lm) * 32 + qk);
#pragma unroll
    for (int mt = 0; mt < 4; ++mt)
#pragma unroll
      for (int nt = 0; nt < 4; ++nt)
        acc[mt][nt] = __builtin_amdgcn_mfma_f32_16x16x32_bf16(af[mt], bfr[nt], acc[mt][nt], 0, 0, 0);
  }

  // C/D layout: col = lane&15, row = (lane>>4)*4 + reg   (m89/m91 verified)
  const int row0 = bm * 128 + wm * 64 + (lane >> 4) * 4;
  const int col0 = bn * 128 + wn * 64 + lm;
#pragma unroll
  for (int mt = 0; mt < 4; ++mt)
#pragma unroll
    for (int nt = 0; nt < 4; ++nt)
#pragma unroll
      for (int rr = 0; rr < 4; ++rr) {
        int row = row0 + mt * 16 + rr;
        int col = col0 + nt * 16;
        float v = acc[mt][nt][rr];
        if (MODE == 0) {
          v += bias[col];
          Cb[(size_t)row * N + col] = f32_to_bf16(v);
        } else {
          v = 1.0f / (1.0f + __expf(-v));
          Cf[(size_t)row * N + col] = v;
        }
      }
}

// ---------------- K3: r[t] = tanh(dot(Z32[t,:], W_rate)) ----------------
__global__ void k_rate(const float* __restrict__ Z, const float* __restrict__ Wr,
                       float* __restrict__ r) {
  const int lane = threadIdx.x & 63;
  const int t = blockIdx.x * 4 + (threadIdx.x >> 6);
  const float4* z4 = (const float4*)(Z + (size_t)t * 512 + lane * 8);
  const float4* w4 = (const float4*)(Wr + lane * 8);
  float4 za = z4[0], zb = z4[1], wa = w4[0], wb = w4[1];
  float acc = za.x * wa.x + za.y * wa.y + za.z * wa.z + za.w * wa.w +
              zb.x * wb.x + zb.y * wb.y + zb.z * wb.z + zb.w * wb.w;
#pragma unroll
  for (int off = 32; off > 0; off >>= 1) acc += __shfl_down(acc, off, 64);
  if (lane == 0) r[t] = tanhf(acc);
}

// ---------------- K4: chunk-parallel recurrence ----------------
// 256 WGs x 1024 threads (16 waves). Wave wv owns chunk cg = wg*16+wv
// (rows [cg*8, cg*8+8)), runs 4 warmup + 8 real steps. Per step the block
// computes logits for all 16 states via fp8 MFMA (A = fp8 states in LDS,
// B = fp8 W_forget^T in VGPRs: wave wv owns cols [32wv, 32wv+32), 64 VGPRs).
__global__ __launch_bounds__(1024) void k_recur(
    const unsigned char* __restrict__ Wf8, const float* __restrict__ Z,
    const float* __restrict__ rArr, const float* __restrict__ ctx0,
    float* __restrict__ out) {
  __shared__ unsigned char Cq[16 * 520];   // fp8(16*c), row stride 520 B
  __shared__ float Lg[16 * 516];           // logits (x256), row stride 516

  const int tid = threadIdx.x;
  const int wv = tid >> 6;
  const int lane = tid & 63;
  const int lm = lane & 15;
  const int qk = (lane >> 4) * 8;

  // B fragments: B[k][n] = 16*Wf[k][n] fp8; Wf8 stored [n][k].
  long Bf[2][16];
  const int nbase = wv * 32;
#pragma unroll
  for (int nt = 0; nt < 2; ++nt)
#pragma unroll
    for (int kt = 0; kt < 16; ++kt)
      Bf[nt][kt] = *(const long*)(Wf8 + (size_t)(nbase + nt * 16 + lm) * 512 + kt * 32 + qk);

  const int g = wv;
  const int cg = blockIdx.x * 16 + g;      // chunk id
  const int colBase = lane * 8;
  float c[8];
  if (cg == 0) {
#pragma unroll
    for (int j = 0; j < 8; ++j) c[j] = ctx0[colBase + j];
  } else {
#pragma unroll
    for (int j = 0; j < 8; ++j) c[j] = 0.f;
  }
  {
    unsigned long long pk = 0;
#pragma unroll
    for (int j = 0; j < 8; ++j)
      pk |= (unsigned long long)f32_to_e4m3(c[j] * 16.0f) << (8 * j);
    *(unsigned long long*)(Cq + g * 520 + colBase) = pk;
  }
  __syncthreads();

  for (int s = 0; s < 12; ++s) {
    f32x4 acc0 = {0.f, 0.f, 0.f, 0.f}, acc1 = {0.f, 0.f, 0.f, 0.f};
#pragma unroll
    for (int kt = 0; kt < 16; ++kt) {
      long a = *(const long*)(Cq + lm * 520 + kt * 32 + qk);
      acc0 = __builtin_amdgcn_mfma_f32_16x16x32_fp8_fp8(a, Bf[0][kt], acc0, 0, 0, 0);
      acc1 = __builtin_amdgcn_mfma_f32_16x16x32_fp8_fp8(a, Bf[1][kt], acc1, 0, 0, 0);
    }
#pragma unroll
    for (int rr = 0; rr < 4; ++rr) {
      Lg[((lane >> 4) * 4 + rr) * 516 + nbase + lm]      = acc0[rr];
      Lg[((lane >> 4) * 4 + rr) * 516 + nbase + 16 + lm] = acc1[rr];
    }
    __syncthreads();

    // softmax over row g (512 logits across 64 lanes x 8)
    float l[8];
    const float* lg = Lg + g * 516 + colBase;
#pragma unroll
    for (int j = 0; j < 8; ++j) l[j] = lg[j] * (1.0f / 256.0f);
    float m = l[0];
#pragma unroll
    for (int j = 1; j < 8; ++j) m = fmaxf(m, l[j]);
#pragma unroll
    for (int off = 1; off < 64; off <<= 1) m = fmaxf(m, __shfl_xor(m, off, 64));
    float sum = 0.f;
#pragma unroll
    for (int j = 0; j < 8; ++j) { l[j] = __expf(l[j] - m); sum += l[j]; }
#pragma unroll
    for (int off = 1; off < 64; off <<= 1) sum += __shfl_xor(sum, off, 64);
    const float inv = 1.0f / sum;

    const int t = cg * 8 - 4 + s;
    if (t >= 0) {
      const float4* z4 = (const float4*)(Z + (size_t)t * 512 + colBase);
      float4 za = z4[0], zb = z4[1];
      float zz[8] = {za.x, za.y, za.z, za.w, zb.x, zb.y, zb.z, zb.w};
      const float rt = rArr[t];
#pragma unroll
      for (int j = 0; j < 8; ++j)
        c[j] = l[j] * inv * c[j] + rt * zz[j];
      if (s >= 4) {
        float4 o0 = {c[0], c[1], c[2], c[3]};
        float4 o1 = {c[4], c[5], c[6], c[7]};
        *(float4*)(out + (size_t)t * 512 + colBase)     = o0;
        *(float4*)(out + (size_t)t * 512 + colBase + 4) = o1;
      }
    }
    unsigned long long pk = 0;
#pragma unroll
    for (int j = 0; j < 8; ++j)
      pk |= (unsigned long long)f32_to_e4m3(c[j] * 16.0f) << (8 * j);
    *(unsigned long long*)(Cq + g * 520 + colBase) = pk;
    __syncthreads();
  }
}

extern "C" void kernel_launch(void* const* d_in, const int* in_sizes, int n_in,
                              void* d_out, int out_size, void* d_ws, size_t ws_size,
                              hipStream_t stream) {
  const float* x1   = (const float*)d_in[0];
  const float* x2   = (const float*)d_in[1];
  const float* ctx0 = (const float*)d_in[2];
  const float* Wl   = (const float*)d_in[3];
  const float* bl   = (const float*)d_in[4];
  const float* We   = (const float*)d_in[5];
  const float* Wr   = (const float*)d_in[6];
  const float* Wf   = (const float*)d_in[7];
  float* out = (float*)d_out;

  // ws layout (Z32 overlays Xb; Xb dead after K1). Total 120,193,024 B.
  char* ws = (char*)d_ws;
  if (ws_size < 120193024u) return;
  unsigned short* Xb  = (unsigned short*)(ws);              // 64 MB
  float*          Z32 = (float*)(ws);                       // 64 MB (overlay)
  unsigned short* WlT = (unsigned short*)(ws + 67108864);   // 1.5 MB
  unsigned short* WeT = (unsigned short*)(ws + 68681728);   // 768 KB
  unsigned char*  Wf8 = (unsigned char*) (ws + 69468160);   // 256 KB
  float*          rb  = (float*)         (ws + 69730304);   // 128 KB
  unsigned short* H   = (unsigned short*)(ws + 69861376);   // 48 MB

  k_convert_x<<<32768, 256, 0, stream>>>(x1, x2, Xb);
  k_convert_w<<<5632, 256, 0, stream>>>(Wl, We, Wf, WlT, WeT, Wf8);
  k_gemm_bt<0><<<1536, 256, 0, stream>>>(Xb, WlT, bl, H, nullptr, 32768, 768, 1024);
  k_gemm_bt<1><<<1024, 256, 0, stream>>>(H, WeT, bl, nullptr, Z32, 32768, 512, 768);
  k_rate<<<8192, 256, 0, stream>>>(Z32, Wr, rb);
  k_recur<<<256, 1024, 0, stream>>>(Wf8, Z32, rb, ctx0, out);
}

// Round 3
// 356.656 us; speedup vs baseline: 1.0717x; 1.0717x over previous
//
#include <hip/hip_runtime.h>
#include <stdint.h>
#include <stddef.h>

// T=32768, D1=D2=512, DIN=1024, HID=768, SZ=512
// K0a: Xb(bf16)[T,1024] = concat(x1,x2)
// K0t: tiled transpose: WlT(bf16)[768,1024], WeT(bf16)[512,768],
//      Wf8(fp8 e4m3, x16)[512,512]=Wf^T
// K1 : H(bf16)[T,768]  = Xb @ Wl + b     (MFMA bf16, async global_load_lds, XCD swizzle)
// K2 : Z32(f32)[T,512] = sigmoid(H @ We) (same; overlays Xb)
// K3 : r(f32)[T]       = tanh(Z32 @ Wr)
// K4 : chunk-parallel recurrence (4096 chunks x 8 steps, 4 warmup steps;
//      per-step contraction ~2.6e-3 -> truncation ~5e-11). W_forget resident
//      in VGPRs as fp8 B-fragments; state fp32 in regs, fp8 copy in LDS.

typedef __attribute__((ext_vector_type(8))) short bf16x8;
typedef __attribute__((ext_vector_type(4))) float f32x4;

__device__ __forceinline__ unsigned short f32_to_bf16(float f) {
  union { float f; unsigned u; } v; v.f = f;
  unsigned u = v.u;
  return (unsigned short)((u + 0x7fffu + ((u >> 16) & 1u)) >> 16);  // RNE
}

// OCP e4m3fn encode, RNE. |x| here is always < 32.
__device__ __forceinline__ unsigned char f32_to_e4m3(float f) {
  float a = fabsf(f);
  unsigned char s = (unsigned char)((__float_as_uint(f) >> 24) & 0x80u);
  if (a >= 448.0f) return s | 0x7Eu;
  if (a < 0.015625f) {
    unsigned m = (unsigned)rintf(a * 512.0f);
    return s | (unsigned char)m;
  }
  unsigned u = __float_as_uint(a);
  unsigned r = u + 0x7FFFFu + ((u >> 20) & 1u);
  unsigned e = (r >> 23) - 120u;
  unsigned m = (r >> 20) & 7u;
  if (e >= 16u) return s | 0x7Eu;
  return s | (unsigned char)((e << 3) | m);
}

__device__ __forceinline__ void async16(const void* g, void* l) {
  // 16B/lane global->LDS DMA; LDS dest = wave-uniform base + lane*16
  __builtin_amdgcn_global_load_lds(
      (const __attribute__((address_space(1))) unsigned int*)g,
      (__attribute__((address_space(3))) unsigned int*)l, 16, 0, 0);
}

// ---------------- K0a ----------------
__global__ void k_convert_x(const float* __restrict__ x1, const float* __restrict__ x2,
                            unsigned short* __restrict__ Xb) {
  int id = blockIdx.x * 256 + threadIdx.x;     // exactly T*1024/4
  int t  = id >> 8;
  int c4 = (id & 255) * 4;
  float4 v;
  if (c4 < 512) v = *(const float4*)(x1 + (size_t)t * 512 + c4);
  else          v = *(const float4*)(x2 + (size_t)t * 512 + (c4 - 512));
  ushort4 o;
  o.x = f32_to_bf16(v.x); o.y = f32_to_bf16(v.y);
  o.z = f32_to_bf16(v.z); o.w = f32_to_bf16(v.w);
  *(ushort4*)(Xb + (size_t)t * 1024 + c4) = o;
}

// ---------------- K0t: tiled weight transpose (coalesced both sides) ----------
// blocks [0,768): Wl[1024x768]->WlT ; [768,1152): We[768x512]->WeT ;
// [1152,1408): Wf[512x512]->Wf8 (fp8, x16). 32x32 tiles, 32x8 threads.
__global__ void k_transpose_w(const float* __restrict__ Wl, const float* __restrict__ We,
                              const float* __restrict__ Wf,
                              unsigned short* __restrict__ WlT,
                              unsigned short* __restrict__ WeT,
                              unsigned char* __restrict__ Wf8) {
  __shared__ float tile[32][33];
  int b = blockIdx.x;
  const float* src; int C, R, tr, tc, mode;
  if (b < 768)       { src = Wl; R = 1024; C = 768; tr = b / 24;  tc = b % 24;  mode = 0; }
  else if (b < 1152) { int j = b - 768;  src = We; R = 768; C = 512; tr = j / 16; tc = j % 16; mode = 1; }
  else               { int j = b - 1152; src = Wf; R = 512; C = 512; tr = j / 16; tc = j % 16; mode = 2; }
  const int tx = threadIdx.x & 31, ty = threadIdx.x >> 5;
  const int r0 = tr * 32, c0 = tc * 32;
#pragma unroll
  for (int p = 0; p < 4; ++p)
    tile[ty + p * 8][tx] = src[(size_t)(r0 + ty + p * 8) * C + c0 + tx];
  __syncthreads();
#pragma unroll
  for (int p = 0; p < 4; ++p) {
    int n = c0 + ty + p * 8;                   // output row (dst is [C][R])
    float v = tile[tx][ty + p * 8];            // stride-33 read: conflict-free
    if (mode == 0)      WlT[(size_t)n * 1024 + r0 + tx] = f32_to_bf16(v);
    else if (mode == 1) WeT[(size_t)n * 768  + r0 + tx] = f32_to_bf16(v);
    else                Wf8[(size_t)n * 512  + r0 + tx] = f32_to_e4m3(v * 16.0f);
  }
}

// ---------------- K1/K2: bf16 MFMA GEMM, C = A[MxK] @ B (B as B^T[NxK]) --------
// m97-style async global_load_lds staging. XCD swizzle: all nb blocks sharing a
// bm land on one XCD (A-row fetched once per XCD, each bm on exactly one XCD).
// MODE 0: bf16 out, +bias.  MODE 1: f32 out, sigmoid.
template <int MODE>
__global__ void k_gemm_bt(const unsigned short* __restrict__ A,
                          const unsigned short* __restrict__ Bt,
                          const float* __restrict__ bias,
                          unsigned short* __restrict__ Cb,
                          float* __restrict__ Cf,
                          int M, int N, int K) {
  __shared__ unsigned short As[128 * 32];
  __shared__ unsigned short Bs[128 * 32];
  const int tid = threadIdx.x;
  const int wv = tid >> 6, lane = tid & 63;
  const int nb = N >> 7;
  const int xcd = blockIdx.x & 7;
  const int s   = blockIdx.x >> 3;
  const int bm  = xcd * (M >> 10) + s / nb;    // M>>10 = 128-rows per XCD
  const int bn  = s % nb;
  const int wm = wv >> 1, wn = wv & 1;         // 2x2 waves, 64x64 each
  f32x4 acc[4][4];
#pragma unroll
  for (int i = 0; i < 4; ++i)
#pragma unroll
    for (int j = 0; j < 4; ++j) acc[i][j] = f32x4{0.f, 0.f, 0.f, 0.f};

  const unsigned short* Ag = A + (size_t)(bm * 128 + (tid >> 2)) * K + (tid & 3) * 8;
  const unsigned short* Bg = Bt + (size_t)(bn * 128 + (tid >> 2)) * K + (tid & 3) * 8;
  unsigned short* AsW = As + wv * 512;         // wave-uniform LDS base (1 KB/wave)
  unsigned short* BsW = Bs + wv * 512;
  const int lm = lane & 15;
  const int qk = (lane >> 4) * 8;

  for (int k0 = 0; k0 < K; k0 += 32) {
    __syncthreads();                           // prev iter's LDS reads complete
    async16(Ag + k0,                  AsW);
    async16(Ag + k0 + (size_t)64 * K, AsW + 2048);
    async16(Bg + k0,                  BsW);
    async16(Bg + k0 + (size_t)64 * K, BsW + 2048);
    __syncthreads();                           // drains vmcnt(0) then barrier
    bf16x8 af[4], bfr[4];
#pragma unroll
    for (int mt = 0; mt < 4; ++mt)
      af[mt] = *(const bf16x8*)(As + (wm * 64 + mt * 16 + lm) * 32 + qk);
#pragma unroll
    for (int nt = 0; nt < 4; ++nt)
      bfr[nt] = *(const bf16x8*)(Bs + (wn * 64 + nt * 16 + lm) * 32 + qk);
#pragma unroll
    for (int mt = 0; mt < 4; ++mt)
#pragma unroll
      for (int nt = 0; nt < 4; ++nt)
        acc[mt][nt] = __builtin_amdgcn_mfma_f32_16x16x32_bf16(af[mt], bfr[nt], acc[mt][nt], 0, 0, 0);
  }

  // C/D layout: col = lane&15, row = (lane>>4)*4 + reg   (m89/m91 verified)
  const int row0 = bm * 128 + wm * 64 + (lane >> 4) * 4;
  const int col0 = bn * 128 + wn * 64 + lm;
#pragma unroll
  for (int mt = 0; mt < 4; ++mt)
#pragma unroll
    for (int nt = 0; nt < 4; ++nt)
#pragma unroll
      for (int rr = 0; rr < 4; ++rr) {
        int row = row0 + mt * 16 + rr;
        int col = col0 + nt * 16;
        float v = acc[mt][nt][rr];
        if (MODE == 0) {
          v += bias[col];
          Cb[(size_t)row * N + col] = f32_to_bf16(v);
        } else {
          v = 1.0f / (1.0f + __expf(-v));
          Cf[(size_t)row * N + col] = v;
        }
      }
}

// ---------------- K3: r[t] = tanh(dot(Z32[t,:], W_rate)) ----------------
__global__ void k_rate(const float* __restrict__ Z, const float* __restrict__ Wr,
                       float* __restrict__ r) {
  const int lane = threadIdx.x & 63;
  const int t = blockIdx.x * 4 + (threadIdx.x >> 6);
  const float4* z4 = (const float4*)(Z + (size_t)t * 512 + lane * 8);
  const float4* w4 = (const float4*)(Wr + lane * 8);
  float4 za = z4[0], zb = z4[1], wa = w4[0], wb = w4[1];
  float acc = za.x * wa.x + za.y * wa.y + za.z * wa.z + za.w * wa.w +
              zb.x * wb.x + zb.y * wb.y + zb.z * wb.z + zb.w * wb.w;
#pragma unroll
  for (int off = 32; off > 0; off >>= 1) acc += __shfl_down(acc, off, 64);
  if (lane == 0) r[t] = tanhf(acc);
}

// ---------------- K4: chunk-parallel recurrence ----------------
// 256 WGs x 1024 threads (16 waves). Wave wv owns chunk cg = wg*16+wv
// (rows [cg*8, cg*8+8)), runs 4 warmup + 8 real steps. Per step the block
// computes logits for all 16 states via fp8 MFMA (A = fp8 states in LDS,
// B = fp8 W_forget^T in VGPRs: wave wv owns cols [32wv, 32wv+32)).
__global__ __launch_bounds__(1024) void k_recur(
    const unsigned char* __restrict__ Wf8, const float* __restrict__ Z,
    const float* __restrict__ rArr, const float* __restrict__ ctx0,
    float* __restrict__ out) {
  __shared__ unsigned char Cq[16 * 520];   // fp8(16*c), row stride 520 B
  __shared__ float Lg[16 * 516];           // logits (x256), row stride 516

  const int tid = threadIdx.x;
  const int wv = tid >> 6;
  const int lane = tid & 63;
  const int lm = lane & 15;
  const int qk = (lane >> 4) * 8;

  long Bf[2][16];
  const int nbase = wv * 32;
#pragma unroll
  for (int nt = 0; nt < 2; ++nt)
#pragma unroll
    for (int kt = 0; kt < 16; ++kt)
      Bf[nt][kt] = *(const long*)(Wf8 + (size_t)(nbase + nt * 16 + lm) * 512 + kt * 32 + qk);

  const int g = wv;
  const int cg = blockIdx.x * 16 + g;      // chunk id
  const int colBase = lane * 8;
  float c[8];
  if (cg == 0) {
#pragma unroll
    for (int j = 0; j < 8; ++j) c[j] = ctx0[colBase + j];
  } else {
#pragma unroll
    for (int j = 0; j < 8; ++j) c[j] = 0.f;
  }
  {
    unsigned long long pk = 0;
#pragma unroll
    for (int j = 0; j < 8; ++j)
      pk |= (unsigned long long)f32_to_e4m3(c[j] * 16.0f) << (8 * j);
    *(unsigned long long*)(Cq + g * 520 + colBase) = pk;
  }
  __syncthreads();

  for (int s = 0; s < 12; ++s) {
    f32x4 acc0 = {0.f, 0.f, 0.f, 0.f}, acc1 = {0.f, 0.f, 0.f, 0.f};
#pragma unroll
    for (int kt = 0; kt < 16; ++kt) {
      long a = *(const long*)(Cq + lm * 520 + kt * 32 + qk);
      acc0 = __builtin_amdgcn_mfma_f32_16x16x32_fp8_fp8(a, Bf[0][kt], acc0, 0, 0, 0);
      acc1 = __builtin_amdgcn_mfma_f32_16x16x32_fp8_fp8(a, Bf[1][kt], acc1, 0, 0, 0);
    }
#pragma unroll
    for (int rr = 0; rr < 4; ++rr) {
      Lg[((lane >> 4) * 4 + rr) * 516 + nbase + lm]      = acc0[rr];
      Lg[((lane >> 4) * 4 + rr) * 516 + nbase + 16 + lm] = acc1[rr];
    }
    __syncthreads();

    float l[8];
    const float* lg = Lg + g * 516 + colBase;
#pragma unroll
    for (int j = 0; j < 8; ++j) l[j] = lg[j] * (1.0f / 256.0f);
    float m = l[0];
#pragma unroll
    for (int j = 1; j < 8; ++j) m = fmaxf(m, l[j]);
#pragma unroll
    for (int off = 1; off < 64; off <<= 1) m = fmaxf(m, __shfl_xor(m, off, 64));
    float sum = 0.f;
#pragma unroll
    for (int j = 0; j < 8; ++j) { l[j] = __expf(l[j] - m); sum += l[j]; }
#pragma unroll
    for (int off = 1; off < 64; off <<= 1) sum += __shfl_xor(sum, off, 64);
    const float inv = 1.0f / sum;

    const int t = cg * 8 - 4 + s;
    if (t >= 0) {
      const float4* z4 = (const float4*)(Z + (size_t)t * 512 + colBase);
      float4 za = z4[0], zb = z4[1];
      float zz[8] = {za.x, za.y, za.z, za.w, zb.x, zb.y, zb.z, zb.w};
      const float rt = rArr[t];
#pragma unroll
      for (int j = 0; j < 8; ++j)
        c[j] = l[j] * inv * c[j] + rt * zz[j];
      if (s >= 4) {
        float4 o0 = {c[0], c[1], c[2], c[3]};
        float4 o1 = {c[4], c[5], c[6], c[7]};
        *(float4*)(out + (size_t)t * 512 + colBase)     = o0;
        *(float4*)(out + (size_t)t * 512 + colBase + 4) = o1;
      }
    }
    unsigned long long pk = 0;
#pragma unroll
    for (int j = 0; j < 8; ++j)
      pk |= (unsigned long long)f32_to_e4m3(c[j] * 16.0f) << (8 * j);
    *(unsigned long long*)(Cq + g * 520 + colBase) = pk;
    __syncthreads();
  }
}

extern "C" void kernel_launch(void* const* d_in, const int* in_sizes, int n_in,
                              void* d_out, int out_size, void* d_ws, size_t ws_size,
                              hipStream_t stream) {
  const float* x1   = (const float*)d_in[0];
  const float* x2   = (const float*)d_in[1];
  const float* ctx0 = (const float*)d_in[2];
  const float* Wl   = (const float*)d_in[3];
  const float* bl   = (const float*)d_in[4];
  const float* We   = (const float*)d_in[5];
  const float* Wr   = (const float*)d_in[6];
  const float* Wf   = (const float*)d_in[7];
  float* out = (float*)d_out;

  // ws layout (Z32 overlays Xb; Xb dead after K1). Total 120,193,024 B.
  char* ws = (char*)d_ws;
  if (ws_size < 120193024u) return;
  unsigned short* Xb  = (unsigned short*)(ws);              // 64 MB
  float*          Z32 = (float*)(ws);                       // 64 MB (overlay)
  unsigned short* WlT = (unsigned short*)(ws + 67108864);   // 1.5 MB
  unsigned short* WeT = (unsigned short*)(ws + 68681728);   // 768 KB
  unsigned char*  Wf8 = (unsigned char*) (ws + 69468160);   // 256 KB
  float*          rb  = (float*)         (ws + 69730304);   // 128 KB
  unsigned short* H   = (unsigned short*)(ws + 69861376);   // 48 MB

  k_convert_x<<<32768, 256, 0, stream>>>(x1, x2, Xb);
  k_transpose_w<<<1408, 256, 0, stream>>>(Wl, We, Wf, WlT, WeT, Wf8);
  k_gemm_bt<0><<<1536, 256, 0, stream>>>(Xb, WlT, bl, H, nullptr, 32768, 768, 1024);
  k_gemm_bt<1><<<1024, 256, 0, stream>>>(H, WeT, bl, nullptr, Z32, 32768, 512, 768);
  k_rate<<<8192, 256, 0, stream>>>(Z32, Wr, rb);
  k_recur<<<256, 1024, 0, stream>>>(Wf8, Z32, rb, ctx0, out);
}

// Round 4
// 346.421 us; speedup vs baseline: 1.1034x; 1.0295x over previous
//
#include <hip/hip_runtime.h>
#include <stdint.h>
#include <stddef.h>

// T=32768, D1=D2=512, DIN=1024, HID=768, SZ=512
// K0a: Xb(bf16)[T,1024] = concat(x1,x2)
// K0t: tiled transpose: WlT(bf16)[768,1024], WeT(bf16)[512,768],
//      Wf8(fp8 e4m3, x16)[512,512]=Wf^T ; tail blocks zero rb[32768]
// K1 : H(bf16)[T,768]  = Xb @ Wl + b     (MFMA bf16, BK=64 async staging, XCD swizzle)
// K2 : Z32(f32)[T,512] = sigmoid(H @ We) + fused partial r = z @ Wr via atomicAdd
// K4 : chunk-parallel recurrence (4096 chunks x 8 steps, 4 warmup steps;
//      per-step contraction ~2.6e-3 -> truncation ~5e-11). W_forget resident
//      in VGPRs as fp8 B-fragments; r finished with tanh at point of use.

typedef __attribute__((ext_vector_type(8))) short bf16x8;
typedef __attribute__((ext_vector_type(4))) float f32x4;

__device__ __forceinline__ unsigned short f32_to_bf16(float f) {
  union { float f; unsigned u; } v; v.f = f;
  unsigned u = v.u;
  return (unsigned short)((u + 0x7fffu + ((u >> 16) & 1u)) >> 16);  // RNE
}

// OCP e4m3fn encode, RNE. |x| here is always < 32.
__device__ __forceinline__ unsigned char f32_to_e4m3(float f) {
  float a = fabsf(f);
  unsigned char s = (unsigned char)((__float_as_uint(f) >> 24) & 0x80u);
  if (a >= 448.0f) return s | 0x7Eu;
  if (a < 0.015625f) {
    unsigned m = (unsigned)rintf(a * 512.0f);
    return s | (unsigned char)m;
  }
  unsigned u = __float_as_uint(a);
  unsigned r = u + 0x7FFFFu + ((u >> 20) & 1u);
  unsigned e = (r >> 23) - 120u;
  unsigned m = (r >> 20) & 7u;
  if (e >= 16u) return s | 0x7Eu;
  return s | (unsigned char)((e << 3) | m);
}

__device__ __forceinline__ void async16(const void* g, void* l) {
  // 16B/lane global->LDS DMA; LDS dest = wave-uniform base + lane*16
  __builtin_amdgcn_global_load_lds(
      (const __attribute__((address_space(1))) unsigned int*)g,
      (__attribute__((address_space(3))) unsigned int*)l, 16, 0, 0);
}

// ---------------- K0a ----------------
__global__ void k_convert_x(const float* __restrict__ x1, const float* __restrict__ x2,
                            unsigned short* __restrict__ Xb) {
  int id = blockIdx.x * 256 + threadIdx.x;     // exactly T*1024/4
  int t  = id >> 8;
  int c4 = (id & 255) * 4;
  float4 v;
  if (c4 < 512) v = *(const float4*)(x1 + (size_t)t * 512 + c4);
  else          v = *(const float4*)(x2 + (size_t)t * 512 + (c4 - 512));
  ushort4 o;
  o.x = f32_to_bf16(v.x); o.y = f32_to_bf16(v.y);
  o.z = f32_to_bf16(v.z); o.w = f32_to_bf16(v.w);
  *(ushort4*)(Xb + (size_t)t * 1024 + c4) = o;
}

// ---------------- K0t: tiled weight transpose + rb zero-fill ------------------
// blocks [0,768): Wl->WlT ; [768,1152): We->WeT ; [1152,1408): Wf->Wf8 ;
// [1408,1440): rb zero-fill (32768 floats).
__global__ void k_transpose_w(const float* __restrict__ Wl, const float* __restrict__ We,
                              const float* __restrict__ Wf,
                              unsigned short* __restrict__ WlT,
                              unsigned short* __restrict__ WeT,
                              unsigned char* __restrict__ Wf8,
                              float* __restrict__ rb) {
  __shared__ float tile[32][33];
  int b = blockIdx.x;
  if (b >= 1408) {                              // rb zero-fill tail
    int idx = (b - 1408) * 256 + threadIdx.x;   // 8192 float4 = 32768 floats
    *(float4*)(rb + idx * 4) = float4{0.f, 0.f, 0.f, 0.f};
    return;
  }
  const float* src; int C, tr, tc, mode;
  if (b < 768)       { src = Wl; C = 768; tr = b / 24;  tc = b % 24;  mode = 0; }
  else if (b < 1152) { int j = b - 768;  src = We; C = 512; tr = j / 16; tc = j % 16; mode = 1; }
  else               { int j = b - 1152; src = Wf; C = 512; tr = j / 16; tc = j % 16; mode = 2; }
  const int tx = threadIdx.x & 31, ty = threadIdx.x >> 5;
  const int r0 = tr * 32, c0 = tc * 32;
#pragma unroll
  for (int p = 0; p < 4; ++p)
    tile[ty + p * 8][tx] = src[(size_t)(r0 + ty + p * 8) * C + c0 + tx];
  __syncthreads();
#pragma unroll
  for (int p = 0; p < 4; ++p) {
    int n = c0 + ty + p * 8;                   // output row (dst is [C][R])
    float v = tile[tx][ty + p * 8];            // stride-33 read: conflict-free
    if (mode == 0)      WlT[(size_t)n * 1024 + r0 + tx] = f32_to_bf16(v);
    else if (mode == 1) WeT[(size_t)n * 768  + r0 + tx] = f32_to_bf16(v);
    else                Wf8[(size_t)n * 512  + r0 + tx] = f32_to_e4m3(v * 16.0f);
  }
}

// ---------------- K1/K2: bf16 MFMA GEMM, C = A[MxK] @ B (B as B^T[NxK]) --------
// BK=64: 32 MFMA per barrier-pair (AITER granularity), async global_load_lds.
// XCD swizzle: all nb blocks sharing a bm land on one XCD.
// MODE 0: bf16 out, +bias. MODE 1: f32 out, sigmoid, fused rate partials
//         (aux = W_rate[512], rate = atomic accumulator[M]).
template <int MODE>
__global__ void k_gemm_bt(const unsigned short* __restrict__ A,
                          const unsigned short* __restrict__ Bt,
                          const float* __restrict__ aux,
                          unsigned short* __restrict__ Cb,
                          float* __restrict__ Cf,
                          float* __restrict__ rate,
                          int M, int N, int K) {
  __shared__ unsigned short As[128 * 64];
  __shared__ unsigned short Bs[128 * 64];
  const int tid = threadIdx.x;
  const int wv = tid >> 6, lane = tid & 63;
  const int nb = N >> 7;
  const int xcd = blockIdx.x & 7;
  const int s   = blockIdx.x >> 3;
  const int bm  = xcd * (M >> 10) + s / nb;    // M>>10 = 128-row tiles per XCD
  const int bn  = s % nb;
  const int wm = wv >> 1, wn = wv & 1;         // 2x2 waves, 64x64 each
  f32x4 acc[4][4];
#pragma unroll
  for (int i = 0; i < 4; ++i)
#pragma unroll
    for (int j = 0; j < 4; ++j) acc[i][j] = f32x4{0.f, 0.f, 0.f, 0.f};

  // staging: lane covers row wv*8+(lane>>3)+32p, cols (lane&7)*8..+8
  const unsigned short* Ag = A + (size_t)(bm * 128 + wv * 8 + (lane >> 3)) * K + (lane & 7) * 8;
  const unsigned short* Bg = Bt + (size_t)(bn * 128 + wv * 8 + (lane >> 3)) * K + (lane & 7) * 8;
  char* AsW = (char*)As + wv * 1024;           // wave-uniform LDS base
  char* BsW = (char*)Bs + wv * 1024;
  const int lm = lane & 15;
  const int qk = (lane >> 4) * 8;

  for (int k0 = 0; k0 < K; k0 += 64) {
    __syncthreads();                           // prev iter's LDS reads complete
#pragma unroll
    for (int p = 0; p < 4; ++p) {
      async16(Ag + k0 + (size_t)(p * 32) * K, AsW + p * 4096);
      async16(Bg + k0 + (size_t)(p * 32) * K, BsW + p * 4096);
    }
    __syncthreads();                           // drains vmcnt(0) then barrier
#pragma unroll
    for (int ko = 0; ko < 2; ++ko) {
      bf16x8 af[4], bfr[4];
#pragma unroll
      for (int mt = 0; mt < 4; ++mt)
        af[mt] = *(const bf16x8*)(As + (wm * 64 + mt * 16 + lm) * 64 + ko * 32 + qk);
#pragma unroll
      for (int nt = 0; nt < 4; ++nt)
        bfr[nt] = *(const bf16x8*)(Bs + (wn * 64 + nt * 16 + lm) * 64 + ko * 32 + qk);
#pragma unroll
      for (int mt = 0; mt < 4; ++mt)
#pragma unroll
        for (int nt = 0; nt < 4; ++nt)
          acc[mt][nt] = __builtin_amdgcn_mfma_f32_16x16x32_bf16(af[mt], bfr[nt], acc[mt][nt], 0, 0, 0);
    }
  }

  // C/D layout: col = lane&15, row = (lane>>4)*4 + reg   (m89/m91 verified)
  const int row0 = bm * 128 + wm * 64 + (lane >> 4) * 4;
  const int col0 = bn * 128 + wn * 64 + lm;
  if (MODE == 0) {
#pragma unroll
    for (int mt = 0; mt < 4; ++mt)
#pragma unroll
      for (int nt = 0; nt < 4; ++nt)
#pragma unroll
        for (int rr = 0; rr < 4; ++rr) {
          int row = row0 + mt * 16 + rr;
          int col = col0 + nt * 16;
          Cb[(size_t)row * N + col] = f32_to_bf16(acc[mt][nt][rr] + aux[col]);
        }
  } else {
    float wr[4];
#pragma unroll
    for (int nt = 0; nt < 4; ++nt) wr[nt] = aux[col0 + nt * 16];
#pragma unroll
    for (int mt = 0; mt < 4; ++mt) {
      float rsum[4] = {0.f, 0.f, 0.f, 0.f};
#pragma unroll
      for (int nt = 0; nt < 4; ++nt)
#pragma unroll
        for (int rr = 0; rr < 4; ++rr) {
          int row = row0 + mt * 16 + rr;
          int col = col0 + nt * 16;
          float v = 1.0f / (1.0f + __expf(-acc[mt][nt][rr]));
          Cf[(size_t)row * N + col] = v;
          rsum[rr] += v * wr[nt];
        }
#pragma unroll
      for (int rr = 0; rr < 4; ++rr) {
        float sv = rsum[rr];
        sv += __shfl_xor(sv, 1, 64);
        sv += __shfl_xor(sv, 2, 64);
        sv += __shfl_xor(sv, 4, 64);
        sv += __shfl_xor(sv, 8, 64);
        if (lm == 0) atomicAdd(&rate[row0 + mt * 16 + rr], sv);
      }
    }
  }
}

// ---------------- K4: chunk-parallel recurrence ----------------
// 256 WGs x 1024 threads (16 waves). Wave wv owns chunk cg = wg*16+wv
// (rows [cg*8, cg*8+8)), 4 warmup + 8 real steps. Per step the block computes
// logits for all 16 states via fp8 MFMA (A = fp8 states in LDS, B = fp8
// W_forget^T in VGPRs: wave wv owns cols [32wv, 32wv+32)). z/r prefetched
// before the MFMA phase so HBM latency overlaps LDS work.
__global__ __launch_bounds__(1024) void k_recur(
    const unsigned char* __restrict__ Wf8, const float* __restrict__ Z,
    const float* __restrict__ rArr, const float* __restrict__ ctx0,
    float* __restrict__ out) {
  __shared__ unsigned char Cq[16 * 520];   // fp8(16*c), row stride 520 B
  __shared__ float Lg[16 * 516];           // logits (x256), row stride 516

  const int tid = threadIdx.x;
  const int wv = tid >> 6;
  const int lane = tid & 63;
  const int lm = lane & 15;
  const int qk = (lane >> 4) * 8;

  long Bf[2][16];
  const int nbase = wv * 32;
#pragma unroll
  for (int nt = 0; nt < 2; ++nt)
#pragma unroll
    for (int kt = 0; kt < 16; ++kt)
      Bf[nt][kt] = *(const long*)(Wf8 + (size_t)(nbase + nt * 16 + lm) * 512 + kt * 32 + qk);

  const int g = wv;
  const int cg = blockIdx.x * 16 + g;      // chunk id
  const int colBase = lane * 8;
  float c[8];
  if (cg == 0) {
#pragma unroll
    for (int j = 0; j < 8; ++j) c[j] = ctx0[colBase + j];
  } else {
#pragma unroll
    for (int j = 0; j < 8; ++j) c[j] = 0.f;
  }
  {
    unsigned long long pk = 0;
#pragma unroll
    for (int j = 0; j < 8; ++j)
      pk |= (unsigned long long)f32_to_e4m3(c[j] * 16.0f) << (8 * j);
    *(unsigned long long*)(Cq + g * 520 + colBase) = pk;
  }
  __syncthreads();

  for (int s = 0; s < 12; ++s) {
    const int t = cg * 8 - 4 + s;
    // prefetch this step's z and r before the MFMA/softmax phase
    float4 za = {0.f, 0.f, 0.f, 0.f}, zb = {0.f, 0.f, 0.f, 0.f};
    float rt = 0.f;
    if (t >= 0) {
      const float4* z4 = (const float4*)(Z + (size_t)t * 512 + colBase);
      za = z4[0]; zb = z4[1];
      rt = tanhf(rArr[t]);
    }

    f32x4 acc0 = {0.f, 0.f, 0.f, 0.f}, acc1 = {0.f, 0.f, 0.f, 0.f};
#pragma unroll
    for (int kt = 0; kt < 16; ++kt) {
      long a = *(const long*)(Cq + lm * 520 + kt * 32 + qk);
      acc0 = __builtin_amdgcn_mfma_f32_16x16x32_fp8_fp8(a, Bf[0][kt], acc0, 0, 0, 0);
      acc1 = __builtin_amdgcn_mfma_f32_16x16x32_fp8_fp8(a, Bf[1][kt], acc1, 0, 0, 0);
    }
#pragma unroll
    for (int rr = 0; rr < 4; ++rr) {
      Lg[((lane >> 4) * 4 + rr) * 516 + nbase + lm]      = acc0[rr];
      Lg[((lane >> 4) * 4 + rr) * 516 + nbase + 16 + lm] = acc1[rr];
    }
    __syncthreads();

    float l[8];
    const float* lg = Lg + g * 516 + colBase;
#pragma unroll
    for (int j = 0; j < 8; ++j) l[j] = lg[j] * (1.0f / 256.0f);
    float m = l[0];
#pragma unroll
    for (int j = 1; j < 8; ++j) m = fmaxf(m, l[j]);
#pragma unroll
    for (int off = 1; off < 64; off <<= 1) m = fmaxf(m, __shfl_xor(m, off, 64));
    float sum = 0.f;
#pragma unroll
    for (int j = 0; j < 8; ++j) { l[j] = __expf(l[j] - m); sum += l[j]; }
#pragma unroll
    for (int off = 1; off < 64; off <<= 1) sum += __shfl_xor(sum, off, 64);
    const float inv = 1.0f / sum;

    if (t >= 0) {
      float zz[8] = {za.x, za.y, za.z, za.w, zb.x, zb.y, zb.z, zb.w};
#pragma unroll
      for (int j = 0; j < 8; ++j)
        c[j] = l[j] * inv * c[j] + rt * zz[j];
      if (s >= 4) {
        float4 o0 = {c[0], c[1], c[2], c[3]};
        float4 o1 = {c[4], c[5], c[6], c[7]};
        *(float4*)(out + (size_t)t * 512 + colBase)     = o0;
        *(float4*)(out + (size_t)t * 512 + colBase + 4) = o1;
      }
    }
    unsigned long long pk = 0;
#pragma unroll
    for (int j = 0; j < 8; ++j)
      pk |= (unsigned long long)f32_to_e4m3(c[j] * 16.0f) << (8 * j);
    *(unsigned long long*)(Cq + g * 520 + colBase) = pk;
    __syncthreads();
  }
}

extern "C" void kernel_launch(void* const* d_in, const int* in_sizes, int n_in,
                              void* d_out, int out_size, void* d_ws, size_t ws_size,
                              hipStream_t stream) {
  const float* x1   = (const float*)d_in[0];
  const float* x2   = (const float*)d_in[1];
  const float* ctx0 = (const float*)d_in[2];
  const float* Wl   = (const float*)d_in[3];
  const float* bl   = (const float*)d_in[4];
  const float* We   = (const float*)d_in[5];
  const float* Wr   = (const float*)d_in[6];
  const float* Wf   = (const float*)d_in[7];
  float* out = (float*)d_out;

  // ws layout (Z32 overlays Xb; Xb dead after K1). Total 120,193,024 B.
  char* ws = (char*)d_ws;
  if (ws_size < 120193024u) return;
  unsigned short* Xb  = (unsigned short*)(ws);              // 64 MB
  float*          Z32 = (float*)(ws);                       // 64 MB (overlay)
  unsigned short* WlT = (unsigned short*)(ws + 67108864);   // 1.5 MB
  unsigned short* WeT = (unsigned short*)(ws + 68681728);   // 768 KB
  unsigned char*  Wf8 = (unsigned char*) (ws + 69468160);   // 256 KB
  float*          rb  = (float*)         (ws + 69730304);   // 128 KB
  unsigned short* H   = (unsigned short*)(ws + 69861376);   // 48 MB

  k_convert_x<<<32768, 256, 0, stream>>>(x1, x2, Xb);
  k_transpose_w<<<1440, 256, 0, stream>>>(Wl, We, Wf, WlT, WeT, Wf8, rb);
  k_gemm_bt<0><<<1536, 256, 0, stream>>>(Xb, WlT, bl, H, nullptr, nullptr, 32768, 768, 1024);
  k_gemm_bt<1><<<1024, 256, 0, stream>>>(H, WeT, Wr, nullptr, Z32, rb, 32768, 512, 768);
  k_recur<<<256, 1024, 0, stream>>>(Wf8, Z32, rb, ctx0, out);
}